// Round 3
// baseline (7029.684 us; speedup 1.0000x reference)
//
#include <hip/hip_runtime.h>
#include <hip/hip_bf16.h>
#include <hip/hip_fp16.h>

#define N_RES   4096
#define MAXD    4608
#define IN_DIM  1024
#define T_STEPS 128
#define B_SZ    128
#define KPRE    3072   // 3 * 1024 (hi*hi | hi*lo | lo*hi)

typedef __attribute__((ext_vector_type(8))) short bf16x8;
typedef __attribute__((ext_vector_type(4))) float f32x4;

__device__ __forceinline__ short f2bf(float x) {
  union { float f; unsigned u; } v; v.f = x;
  unsigned r = v.u + 0x7fffu + ((v.u >> 16) & 1u);
  return (short)(r >> 16);
}
__device__ __forceinline__ float bf2f(short b) {
  union { float f; unsigned u; } v; v.u = ((unsigned)(unsigned short)b) << 16;
  return v.f;
}

__device__ __forceinline__ void gload16(const void* g, void* l) {
  __builtin_amdgcn_global_load_lds(
      (const __attribute__((address_space(1))) void*)g,
      (__attribute__((address_space(3))) void*)l,
      16, 0, 0);
}

// ---------------- zero ONLY the padding columns [4096,4608) ----------------
__global__ void k_zero_pad(float* __restrict__ out) {
  int row = blockIdx.x;            // 16384 rows (T*B)
  int t = threadIdx.x;             // 128 threads * float4 = 512 cols
  *(float4*)(out + (size_t)row * MAXD + N_RES + t * 4) = float4{0.f, 0.f, 0.f, 0.f};
}

// ---------------- init state from state0 ----------------
__global__ void k_init_state(const float* __restrict__ s0,
                             float* __restrict__ sF, short* __restrict__ sB) {
  int i = blockIdx.x * 256 + threadIdx.x;   // 128*4096 total
  int m = i >> 12, n = i & 4095;
  float v = s0[m * MAXD + n];
  sF[i] = v;
  sB[i] = f2bf(v);
}

// ---------------- transpose W_res -> bf16 [n][k] ----------------
__global__ void k_wres_t(const float* __restrict__ W, short* __restrict__ bt) {
  __shared__ float tile[64][65];
  int k0 = blockIdx.y * 64, n0 = blockIdx.x * 64;
  int tx = threadIdx.x & 63, ty = threadIdx.x >> 6;   // 256 thr
  #pragma unroll
  for (int r = 0; r < 64; r += 4)
    tile[r + ty][tx] = W[(long)(k0 + r + ty) * N_RES + n0 + tx];
  __syncthreads();
  #pragma unroll
  for (int r = 0; r < 64; r += 4)
    bt[(long)(n0 + r + ty) * N_RES + k0 + tx] = f2bf(tile[tx][r + ty]);
}

// ---------------- build B2 = [Whi | Wlo | Whi] rows of [W_in;W_gate] ----------------
__global__ void k_build_b2(const float* __restrict__ Win,
                           const float* __restrict__ Wg, short* __restrict__ B2) {
  int r = blockIdx.x;   // 16384 rows
  const float* src = (r < N_RES) ? (Win + (long)r * IN_DIM)
                                 : (Wg + (long)(r - N_RES) * IN_DIM);
  short* dst = B2 + (long)r * KPRE;
  for (int c = threadIdx.x; c < IN_DIM; c += 256) {
    float x = src[c];
    short h = f2bf(x);
    short l = f2bf(x - bf2f(h));
    dst[c] = h; dst[IN_DIM + c] = l; dst[2 * IN_DIM + c] = h;
  }
}

// ---------------- build A2 chunk = [Xhi | Xhi | Xlo] ----------------
__global__ void k_build_a2(const float* __restrict__ x, short* __restrict__ A2, int t0) {
  int r = blockIdx.x;   // Tc*128 rows
  const float* src = x + (long)(t0 * B_SZ + r) * IN_DIM;
  short* dst = A2 + (long)r * KPRE;
  for (int c = threadIdx.x; c < IN_DIM; c += 256) {
    float v = src[c];
    short h = f2bf(v);
    short l = f2bf(v - bf2f(h));
    dst[c] = h; dst[IN_DIM + c] = h; dst[2 * IN_DIM + c] = l;
  }
}

// ---------------- precompute GEMM: C = A2 @ B2^T ----------------
// 128x128 tile, BK=64, grouped raster (GROUP_M=32), XOR-swizzled LDS.
__global__ __launch_bounds__(256) void k_gemm_pre(
    const short* __restrict__ A2, const short* __restrict__ B2,
    _Float16* __restrict__ ip, _Float16* __restrict__ gates, int Mtiles) {
  __shared__ short lA[128 * 64];
  __shared__ short lB[128 * 64];
  int tid = threadIdx.x, lane = tid & 63, wid = tid >> 6;
  int wm = wid >> 1, wn = wid & 1;

  int bid = blockIdx.x;
  int GM = Mtiles < 32 ? Mtiles : 32;
  int grp = bid / (GM * 128);
  int gm0 = grp * GM;
  int rem = Mtiles - gm0; if (rem > GM) rem = GM;
  int loc = bid - grp * (GM * 128);
  int mt = gm0 + loc % rem;
  int nt = loc / rem;
  long m0 = (long)mt * 128, n0 = (long)nt * 128;

  int srcCol = ((lane & 7) ^ (lane >> 3)) * 8;   // shorts, pre-swizzled source col
  int rowLo = lane >> 3;

  f32x4 acc[4][4] = {};
  for (int k0 = 0; k0 < KPRE; k0 += 64) {
    #pragma unroll
    for (int is = 0; is < 4; ++is) {
      int c = is * 4 + wid;
      int row = c * 8 + rowLo;
      gload16(A2 + (m0 + row) * KPRE + k0 + srcCol, lA + c * 512);
      gload16(B2 + (n0 + row) * KPRE + k0 + srcCol, lB + c * 512);
    }
    asm volatile("s_waitcnt vmcnt(0)" ::: "memory");
    __syncthreads();
    #pragma unroll
    for (int kk = 0; kk < 64; kk += 32) {
      int colS = (kk + (lane >> 4) * 8) ^ ((lane & 7) << 3);   // swizzled read col
      bf16x8 aF[4], bF[4];
      #pragma unroll
      for (int i = 0; i < 4; ++i)
        aF[i] = *(const bf16x8*)&lA[(wm * 64 + i * 16 + (lane & 15)) * 64 + colS];
      #pragma unroll
      for (int j = 0; j < 4; ++j)
        bF[j] = *(const bf16x8*)&lB[(wn * 64 + j * 16 + (lane & 15)) * 64 + colS];
      #pragma unroll
      for (int i = 0; i < 4; ++i)
        #pragma unroll
        for (int j = 0; j < 4; ++j)
          acc[i][j] = __builtin_amdgcn_mfma_f32_16x16x32_bf16(aF[i], bF[j], acc[i][j], 0, 0, 0);
    }
    __syncthreads();
  }
  #pragma unroll
  for (int i = 0; i < 4; ++i)
    #pragma unroll
    for (int j = 0; j < 4; ++j)
      #pragma unroll
      for (int q = 0; q < 4; ++q) {
        long m = m0 + wm * 64 + i * 16 + (lane >> 4) * 4 + q;
        long n = n0 + wn * 64 + j * 16 + (lane & 15);
        float v = acc[i][j][q];
        if (n < N_RES) {
          ip[m * N_RES + n] = (_Float16)v;
        } else {
          gates[m * 12288 + (n - N_RES)] = (_Float16)(1.f / (1.f + __expf(-v)));
        }
      }
}

// ---------------- per-step GEMM: res = prev_bf16 @ WresBT^T + fused epilogue ----
// BM=64 x BN=32, 256 blocks, XCD-aware mapping (n-slice pinned to one XCD's L2).
// BK=64, 4 LDS buffers (48 KiB), depth-3 counted-vmcnt pipeline, raw s_barrier.
__global__ __launch_bounds__(256) void k_step(
    const short* __restrict__ Abf,      // state bf16 (read buf)  [128][4096]
    const short* __restrict__ Bt,       // Wres^T bf16 [4096][4096]
    const _Float16* __restrict__ ip,    // + tloc*128*4096
    const _Float16* __restrict__ gates, // + tloc*128*12288
    float* __restrict__ sF,             // state fp32 [128][4096]
    short* __restrict__ sBw,            // state bf16 (write buf)
    float* __restrict__ out) {          // d_out + t*128*4608
  __shared__ short lA[4][64 * 64];      // 4 x 8 KiB
  __shared__ short lB[4][32 * 64];      // 4 x 4 KiB
  int tid = threadIdx.x, lane = tid & 63, wid = tid >> 6;
  int wm = wid >> 1, wn = wid & 1;      // wave tile: rows wm*32..+32, cols wn*16..+16

  // XCD-aware mapping: blockIdx%8 = XCD (round-robin); 16 n-tiles + both
  // m-halves per XCD -> Wres slice (4 MB) stays in that XCD's L2 across steps.
  int b = blockIdx.x;                   // 0..255
  int slot = b >> 3;                    // 0..31
  int n_tile = (b & 7) * 16 + (slot & 15);
  int m_half = slot >> 4;
  int n0 = n_tile * 32;
  int m0 = m_half * 64;

  // staging geometry: tile A = 64x64 shorts (512 x 16B chunks), B = 32x64 (256).
  // chunk c: row=c>>3, src colchunk=(c&7)^(row&7); dest linear (c*16B).
  const int cA0 = tid, cA1 = 256 + tid, cB0 = tid;
  const short* pA0 = Abf + (size_t)(m0 + (cA0 >> 3)) * N_RES + (((cA0 & 7) ^ ((cA0 >> 3) & 7)) * 8);
  const short* pA1 = Abf + (size_t)(m0 + (cA1 >> 3)) * N_RES + (((cA1 & 7) ^ ((cA1 >> 3) & 7)) * 8);
  const short* pB0 = Bt  + (size_t)(n0 + (cB0 >> 3)) * N_RES + (((cB0 & 7) ^ ((cB0 >> 3) & 7)) * 8);

  #define STAGE(kt, bi)                                \
    {                                                  \
      int k0s = (kt) * 64;                             \
      gload16(pA0 + k0s, &lA[bi][cA0 * 8]);            \
      gload16(pA1 + k0s, &lA[bi][cA1 * 8]);            \
      gload16(pB0 + k0s, &lB[bi][cB0 * 8]);            \
    }

  f32x4 acc[2] = {};

  STAGE(0, 0); STAGE(1, 1); STAGE(2, 2);               // 9 loads in flight

  for (int kt = 0; kt < 64; ++kt) {
    // this wave's loads for buf[kt&3] are the 3 oldest of 9 -> drain to 6
    asm volatile("s_waitcnt vmcnt(6)" ::: "memory");
    __builtin_amdgcn_s_barrier();                      // all waves' loads landed;
                                                       // all waves done reading buf[(kt+3)&3]
    STAGE((kt + 3) & 63, (kt + 3) & 3);                // tail wraps: harmless re-stage
    int bi = kt & 3;
    #pragma unroll
    for (int kk = 0; kk < 64; kk += 32) {
      int colS = (kk + (lane >> 4) * 8) ^ ((lane & 7) << 3);
      bf16x8 aF0 = *(const bf16x8*)&lA[bi][(wm * 32 + (lane & 15)) * 64 + colS];
      bf16x8 aF1 = *(const bf16x8*)&lA[bi][(wm * 32 + 16 + (lane & 15)) * 64 + colS];
      bf16x8 bF  = *(const bf16x8*)&lB[bi][(wn * 16 + (lane & 15)) * 64 + colS];
      acc[0] = __builtin_amdgcn_mfma_f32_16x16x32_bf16(aF0, bF, acc[0], 0, 0, 0);
      acc[1] = __builtin_amdgcn_mfma_f32_16x16x32_bf16(aF1, bF, acc[1], 0, 0, 0);
    }
  }
  #undef STAGE

  #pragma unroll
  for (int i = 0; i < 2; ++i)
    #pragma unroll
    for (int q = 0; q < 4; ++q) {
      int m = m0 + wm * 32 + i * 16 + (lane >> 4) * 4 + q;
      int n = n0 + wn * 16 + (lane & 15);
      float res = acc[i][q];
      long idx = (long)m * N_RES + n;
      float prev = sF[idx];
      float ipv = (float)ip[idx];
      const _Float16* grow = gates + (long)m * 12288 + n;
      float ig = (float)grow[0];
      float fg = (float)grow[4096];
      float og = (float)grow[8192];
      float s = 0.9f * (fg * prev) + 0.1f * tanhf(ig * (ipv + res));
      s = og * s;
      if (s > 0.5f) s -= 0.5f;
      out[(long)m * MAXD + n] = s;
      sF[idx] = s;
      sBw[idx] = f2bf(s);
    }
}

extern "C" void kernel_launch(void* const* d_in, const int* in_sizes, int n_in,
                              void* d_out, int out_size, void* d_ws, size_t ws_size,
                              hipStream_t stream) {
  const float* x      = (const float*)d_in[0];
  const float* state0 = (const float*)d_in[1];
  const float* W_res  = (const float*)d_in[2];
  const float* W_in   = (const float*)d_in[3];
  const float* W_gate = (const float*)d_in[4];
  float* out = (float*)d_out;
  char* ws = (char*)d_ws;

  size_t off = 0;
  short* WresBT = (short*)(ws + off); off += (size_t)N_RES * N_RES * 2;       // 33.6 MB
  short* B2     = (short*)(ws + off); off += (size_t)16384 * KPRE * 2;        // 100.7 MB
  float* sF     = (float*)(ws + off); off += (size_t)B_SZ * N_RES * 4;        // 2 MB
  short* sB0    = (short*)(ws + off); off += (size_t)B_SZ * N_RES * 2;        // 1 MB
  short* sB1    = (short*)(ws + off); off += (size_t)B_SZ * N_RES * 2;        // 1 MB
  size_t fixed = off;
  size_t per = (size_t)B_SZ * KPRE * 2 + (size_t)B_SZ * N_RES * 2 + (size_t)B_SZ * 12288 * 2;

  int Tc = T_STEPS;
  while (Tc > 1 && fixed + (size_t)Tc * per > ws_size) Tc >>= 1;

  short*     A2  = (short*)(ws + fixed);
  _Float16*  ipb = (_Float16*)(ws + fixed + (size_t)Tc * B_SZ * KPRE * 2);
  _Float16*  gtb = (_Float16*)(ws + fixed + (size_t)Tc * B_SZ * KPRE * 2
                               + (size_t)Tc * B_SZ * N_RES * 2);

  k_zero_pad<<<T_STEPS * B_SZ, 128, 0, stream>>>(out);
  k_init_state<<<(B_SZ * N_RES) / 256, 256, 0, stream>>>(state0, sF, sB0);
  k_wres_t<<<dim3(64, 64), 256, 0, stream>>>(W_res, WresBT);
  k_build_b2<<<16384, 256, 0, stream>>>(W_in, W_gate, B2);

  for (int t0 = 0; t0 < T_STEPS; t0 += Tc) {
    k_build_a2<<<Tc * B_SZ, 256, 0, stream>>>(x, A2, t0);
    k_gemm_pre<<<Tc * 128, 256, 0, stream>>>(A2, B2, ipb, gtb, Tc);
    for (int tl = 0; tl < Tc; ++tl) {
      int t = t0 + tl;
      const short* Ar = (t & 1) ? sB1 : sB0;
      short*       Aw = (t & 1) ? sB0 : sB1;
      k_step<<<256, 256, 0, stream>>>(
          Ar, WresBT,
          ipb + (size_t)tl * B_SZ * N_RES,
          gtb + (size_t)tl * B_SZ * 12288,
          sF, Aw,
          out + (size_t)t * B_SZ * MAXD);
    }
  }
}

// Round 4
// 6175.288 us; speedup vs baseline: 1.1384x; 1.1384x over previous
//
#include <hip/hip_runtime.h>
#include <hip/hip_bf16.h>
#include <hip/hip_fp16.h>

#define N_RES   4096
#define MAXD    4608
#define IN_DIM  1024
#define T_STEPS 128
#define B_SZ    128
#define KPRE    3072   // 3 * 1024 (hi*hi | hi*lo | lo*hi)

typedef __attribute__((ext_vector_type(8))) short bf16x8;
typedef __attribute__((ext_vector_type(4))) float f32x4;

__device__ __forceinline__ short f2bf(float x) {
  union { float f; unsigned u; } v; v.f = x;
  unsigned r = v.u + 0x7fffu + ((v.u >> 16) & 1u);
  return (short)(r >> 16);
}
__device__ __forceinline__ float bf2f(short b) {
  union { float f; unsigned u; } v; v.u = ((unsigned)(unsigned short)b) << 16;
  return v.f;
}

__device__ __forceinline__ void gload16(const void* g, void* l) {
  __builtin_amdgcn_global_load_lds(
      (const __attribute__((address_space(1))) void*)g,
      (__attribute__((address_space(3))) void*)l,
      16, 0, 0);
}

// ---------------- zero ONLY the padding columns [4096,4608) ----------------
__global__ void k_zero_pad(float* __restrict__ out) {
  int row = blockIdx.x;            // 16384 rows (T*B)
  int t = threadIdx.x;             // 128 threads * float4 = 512 cols
  *(float4*)(out + (size_t)row * MAXD + N_RES + t * 4) = float4{0.f, 0.f, 0.f, 0.f};
}

// ---------------- init state from state0 ----------------
__global__ void k_init_state(const float* __restrict__ s0,
                             float* __restrict__ sF, short* __restrict__ sB) {
  int i = blockIdx.x * 256 + threadIdx.x;   // 128*4096 total
  int m = i >> 12, n = i & 4095;
  float v = s0[m * MAXD + n];
  sF[i] = v;
  sB[i] = f2bf(v);
}

// ---------------- transpose W_res -> bf16 [n][k] ----------------
__global__ void k_wres_t(const float* __restrict__ W, short* __restrict__ bt) {
  __shared__ float tile[64][65];
  int k0 = blockIdx.y * 64, n0 = blockIdx.x * 64;
  int tx = threadIdx.x & 63, ty = threadIdx.x >> 6;   // 256 thr
  #pragma unroll
  for (int r = 0; r < 64; r += 4)
    tile[r + ty][tx] = W[(long)(k0 + r + ty) * N_RES + n0 + tx];
  __syncthreads();
  #pragma unroll
  for (int r = 0; r < 64; r += 4)
    bt[(long)(n0 + r + ty) * N_RES + k0 + tx] = f2bf(tile[tx][r + ty]);
}

// ---------------- build B2 = [Whi | Wlo | Whi] rows of [W_in;W_gate] ----------------
__global__ void k_build_b2(const float* __restrict__ Win,
                           const float* __restrict__ Wg, short* __restrict__ B2) {
  int r = blockIdx.x;   // 16384 rows
  const float* src = (r < N_RES) ? (Win + (long)r * IN_DIM)
                                 : (Wg + (long)(r - N_RES) * IN_DIM);
  short* dst = B2 + (long)r * KPRE;
  for (int c = threadIdx.x; c < IN_DIM; c += 256) {
    float x = src[c];
    short h = f2bf(x);
    short l = f2bf(x - bf2f(h));
    dst[c] = h; dst[IN_DIM + c] = l; dst[2 * IN_DIM + c] = h;
  }
}

// ---------------- build A2 chunk = [Xhi | Xhi | Xlo] ----------------
__global__ void k_build_a2(const float* __restrict__ x, short* __restrict__ A2, int t0) {
  int r = blockIdx.x;   // Tc*128 rows
  const float* src = x + (long)(t0 * B_SZ + r) * IN_DIM;
  short* dst = A2 + (long)r * KPRE;
  for (int c = threadIdx.x; c < IN_DIM; c += 256) {
    float v = src[c];
    short h = f2bf(v);
    short l = f2bf(v - bf2f(h));
    dst[c] = h; dst[IN_DIM + c] = h; dst[2 * IN_DIM + c] = l;
  }
}

// ---------------- precompute GEMM: C = A2 @ B2^T ----------------
// 128x128 tile, BK=64, grouped raster (GROUP_M=32), XOR-swizzled LDS.
__global__ __launch_bounds__(256) void k_gemm_pre(
    const short* __restrict__ A2, const short* __restrict__ B2,
    _Float16* __restrict__ ip, _Float16* __restrict__ gates, int Mtiles) {
  __shared__ short lA[128 * 64];
  __shared__ short lB[128 * 64];
  int tid = threadIdx.x, lane = tid & 63, wid = tid >> 6;
  int wm = wid >> 1, wn = wid & 1;

  int bid = blockIdx.x;
  int GM = Mtiles < 32 ? Mtiles : 32;
  int grp = bid / (GM * 128);
  int gm0 = grp * GM;
  int rem = Mtiles - gm0; if (rem > GM) rem = GM;
  int loc = bid - grp * (GM * 128);
  int mt = gm0 + loc % rem;
  int nt = loc / rem;
  long m0 = (long)mt * 128, n0 = (long)nt * 128;

  int srcCol = ((lane & 7) ^ (lane >> 3)) * 8;   // shorts, pre-swizzled source col
  int rowLo = lane >> 3;

  f32x4 acc[4][4] = {};
  for (int k0 = 0; k0 < KPRE; k0 += 64) {
    #pragma unroll
    for (int is = 0; is < 4; ++is) {
      int c = is * 4 + wid;
      int row = c * 8 + rowLo;
      gload16(A2 + (m0 + row) * KPRE + k0 + srcCol, lA + c * 512);
      gload16(B2 + (n0 + row) * KPRE + k0 + srcCol, lB + c * 512);
    }
    asm volatile("s_waitcnt vmcnt(0)" ::: "memory");
    __syncthreads();
    #pragma unroll
    for (int kk = 0; kk < 64; kk += 32) {
      int colS = (kk + (lane >> 4) * 8) ^ ((lane & 7) << 3);   // swizzled read col
      bf16x8 aF[4], bF[4];
      #pragma unroll
      for (int i = 0; i < 4; ++i)
        aF[i] = *(const bf16x8*)&lA[(wm * 64 + i * 16 + (lane & 15)) * 64 + colS];
      #pragma unroll
      for (int j = 0; j < 4; ++j)
        bF[j] = *(const bf16x8*)&lB[(wn * 64 + j * 16 + (lane & 15)) * 64 + colS];
      #pragma unroll
      for (int i = 0; i < 4; ++i)
        #pragma unroll
        for (int j = 0; j < 4; ++j)
          acc[i][j] = __builtin_amdgcn_mfma_f32_16x16x32_bf16(aF[i], bF[j], acc[i][j], 0, 0, 0);
    }
    __syncthreads();
  }
  #pragma unroll
  for (int i = 0; i < 4; ++i)
    #pragma unroll
    for (int j = 0; j < 4; ++j)
      #pragma unroll
      for (int q = 0; q < 4; ++q) {
        long m = m0 + wm * 64 + i * 16 + (lane >> 4) * 4 + q;
        long n = n0 + wn * 64 + j * 16 + (lane & 15);
        float v = acc[i][j][q];
        if (n < N_RES) {
          ip[m * N_RES + n] = (_Float16)v;
        } else {
          gates[m * 12288 + (n - N_RES)] = (_Float16)(1.f / (1.f + __expf(-v)));
        }
      }
}

// ---------------- per-step GEMM: res = prev_bf16 @ WresBT^T + fused epilogue ----
// BM=64 x BN=32, 256 blocks, 512 threads (8 waves = 2/SIMD for latency hiding).
// BK=128, double-buffered LDS (48 KiB), proven 2-phase: stage(t+1) || compute(t).
__global__ __launch_bounds__(512) void k_step(
    const short* __restrict__ Abf,      // state bf16 (read buf)  [128][4096]
    const short* __restrict__ Bt,       // Wres^T bf16 [4096][4096]
    const _Float16* __restrict__ ip,    // + tloc*128*4096
    const _Float16* __restrict__ gates, // + tloc*128*12288
    float* __restrict__ sF,             // state fp32 [128][4096]
    short* __restrict__ sBw,            // state bf16 (write buf)
    float* __restrict__ out) {          // d_out + t*128*4608
  __shared__ short lA[2][64 * 128];     // 2 x 16 KiB
  __shared__ short lB[2][32 * 128];     // 2 x 8 KiB
  int tid = threadIdx.x, lane = tid & 63, wid = tid >> 6;   // 8 waves
  int wm = wid >> 1, wn = wid & 1;      // wave tile: 16 rows (wm*16) x 16 cols (wn*16)

  // XCD-aware mapping: blockIdx%8 = XCD; n-slice pinned per XCD.
  int b = blockIdx.x;                   // 0..255
  int slot = b >> 3;                    // 0..31
  int n_tile = (b & 7) * 16 + (slot & 15);
  int m_half = slot >> 4;
  int n0 = n_tile * 32;
  int m0 = m_half * 64;

  // staging geometry: A tile 64x128 shorts = 1024 16B-chunks (2/thread),
  // B tile 32x128 = 512 chunks (1/thread).
  // chunk c: row=c>>4, src colchunk=(c&15)^(row&7); dest linear c*16B.
  const int cA0 = tid, cA1 = 512 + tid, cB0 = tid;
  const short* pA0 = Abf + (size_t)(m0 + (cA0 >> 4)) * N_RES + (((cA0 & 15) ^ ((cA0 >> 4) & 7)) * 8);
  const short* pA1 = Abf + (size_t)(m0 + (cA1 >> 4)) * N_RES + (((cA1 & 15) ^ ((cA1 >> 4) & 7)) * 8);
  const short* pB0 = Bt  + (size_t)(n0 + (cB0 >> 4)) * N_RES + (((cB0 & 15) ^ ((cB0 >> 4) & 7)) * 8);

  #define STAGE(kt, bi)                                \
    {                                                  \
      int k0s = (kt) * 128;                            \
      gload16(pA0 + k0s, &lA[bi][cA0 * 8]);            \
      gload16(pA1 + k0s, &lA[bi][cA1 * 8]);            \
      gload16(pB0 + k0s, &lB[bi][cB0 * 8]);            \
    }

  f32x4 acc = {};

  STAGE(0, 0);
  asm volatile("s_waitcnt vmcnt(0)" ::: "memory");
  __syncthreads();

  for (int kt = 0; kt < 32; ++kt) {
    int cur = kt & 1;
    if (kt < 31) STAGE(kt + 1, cur ^ 1);
    #pragma unroll
    for (int kk = 0; kk < 128; kk += 32) {
      int colS = (kk + (lane >> 4) * 8) ^ ((lane & 7) << 3);
      bf16x8 aF = *(const bf16x8*)&lA[cur][(wm * 16 + (lane & 15)) * 128 + colS];
      bf16x8 bF = *(const bf16x8*)&lB[cur][(wn * 16 + (lane & 15)) * 128 + colS];
      acc = __builtin_amdgcn_mfma_f32_16x16x32_bf16(aF, bF, acc, 0, 0, 0);
    }
    asm volatile("s_waitcnt vmcnt(0)" ::: "memory");
    __syncthreads();
  }
  #undef STAGE

  #pragma unroll
  for (int q = 0; q < 4; ++q) {
    int m = m0 + wm * 16 + (lane >> 4) * 4 + q;
    int n = n0 + wn * 16 + (lane & 15);
    float res = acc[q];
    long idx = (long)m * N_RES + n;
    float prev = sF[idx];
    float ipv = (float)ip[idx];
    const _Float16* grow = gates + (long)m * 12288 + n;
    float ig = (float)grow[0];
    float fg = (float)grow[4096];
    float og = (float)grow[8192];
    float s = 0.9f * (fg * prev) + 0.1f * tanhf(ig * (ipv + res));
    s = og * s;
    if (s > 0.5f) s -= 0.5f;
    out[(long)m * MAXD + n] = s;
    sF[idx] = s;
    sBw[idx] = f2bf(s);
  }
}

extern "C" void kernel_launch(void* const* d_in, const int* in_sizes, int n_in,
                              void* d_out, int out_size, void* d_ws, size_t ws_size,
                              hipStream_t stream) {
  const float* x      = (const float*)d_in[0];
  const float* state0 = (const float*)d_in[1];
  const float* W_res  = (const float*)d_in[2];
  const float* W_in   = (const float*)d_in[3];
  const float* W_gate = (const float*)d_in[4];
  float* out = (float*)d_out;
  char* ws = (char*)d_ws;

  size_t off = 0;
  short* WresBT = (short*)(ws + off); off += (size_t)N_RES * N_RES * 2;       // 33.6 MB
  short* B2     = (short*)(ws + off); off += (size_t)16384 * KPRE * 2;        // 100.7 MB
  float* sF     = (float*)(ws + off); off += (size_t)B_SZ * N_RES * 4;        // 2 MB
  short* sB0    = (short*)(ws + off); off += (size_t)B_SZ * N_RES * 2;        // 1 MB
  short* sB1    = (short*)(ws + off); off += (size_t)B_SZ * N_RES * 2;        // 1 MB
  size_t fixed = off;
  size_t per = (size_t)B_SZ * KPRE * 2 + (size_t)B_SZ * N_RES * 2 + (size_t)B_SZ * 12288 * 2;

  int Tc = T_STEPS;
  while (Tc > 1 && fixed + (size_t)Tc * per > ws_size) Tc >>= 1;

  short*     A2  = (short*)(ws + fixed);
  _Float16*  ipb = (_Float16*)(ws + fixed + (size_t)Tc * B_SZ * KPRE * 2);
  _Float16*  gtb = (_Float16*)(ws + fixed + (size_t)Tc * B_SZ * KPRE * 2
                               + (size_t)Tc * B_SZ * N_RES * 2);

  k_zero_pad<<<T_STEPS * B_SZ, 128, 0, stream>>>(out);
  k_init_state<<<(B_SZ * N_RES) / 256, 256, 0, stream>>>(state0, sF, sB0);
  k_wres_t<<<dim3(64, 64), 256, 0, stream>>>(W_res, WresBT);
  k_build_b2<<<16384, 256, 0, stream>>>(W_in, W_gate, B2);

  for (int t0 = 0; t0 < T_STEPS; t0 += Tc) {
    k_build_a2<<<Tc * B_SZ, 256, 0, stream>>>(x, A2, t0);
    k_gemm_pre<<<Tc * 128, 256, 0, stream>>>(A2, B2, ipb, gtb, Tc);
    for (int tl = 0; tl < Tc; ++tl) {
      int t = t0 + tl;
      const short* Ar = (t & 1) ? sB1 : sB0;
      short*       Aw = (t & 1) ? sB0 : sB1;
      k_step<<<256, 512, 0, stream>>>(
          Ar, WresBT,
          ipb + (size_t)tl * B_SZ * N_RES,
          gtb + (size_t)tl * B_SZ * 12288,
          sF, Aw,
          out + (size_t)t * B_SZ * MAXD);
    }
  }
}

// Round 5
// 5551.916 us; speedup vs baseline: 1.2662x; 1.1123x over previous
//
#include <hip/hip_runtime.h>
#include <hip/hip_bf16.h>
#include <hip/hip_fp16.h>

#define N_RES   4096
#define MAXD    4608
#define IN_DIM  1024
#define T_STEPS 128
#define B_SZ    128
#define KPRE    3072   // 3 * 1024 (hi*hi | hi*lo | lo*hi)

typedef __attribute__((ext_vector_type(8))) short bf16x8;
typedef __attribute__((ext_vector_type(4))) float f32x4;

__device__ __forceinline__ short f2bf(float x) {
  union { float f; unsigned u; } v; v.f = x;
  unsigned r = v.u + 0x7fffu + ((v.u >> 16) & 1u);
  return (short)(r >> 16);
}
__device__ __forceinline__ float bf2f(short b) {
  union { float f; unsigned u; } v; v.u = ((unsigned)(unsigned short)b) << 16;
  return v.f;
}

__device__ __forceinline__ void gload16(const void* g, void* l) {
  __builtin_amdgcn_global_load_lds(
      (const __attribute__((address_space(1))) void*)g,
      (__attribute__((address_space(3))) void*)l,
      16, 0, 0);
}

// ---------------- zero ONLY the padding columns [4096,4608) ----------------
__global__ void k_zero_pad(float* __restrict__ out) {
  int row = blockIdx.x;            // 16384 rows (T*B)
  int t = threadIdx.x;             // 128 threads * float4 = 512 cols
  *(float4*)(out + (size_t)row * MAXD + N_RES + t * 4) = float4{0.f, 0.f, 0.f, 0.f};
}

// ---------------- init state from state0 ----------------
__global__ void k_init_state(const float* __restrict__ s0,
                             float* __restrict__ sF, short* __restrict__ sB) {
  int i = blockIdx.x * 256 + threadIdx.x;   // 128*4096 total
  int m = i >> 12, n = i & 4095;
  float v = s0[m * MAXD + n];
  sF[i] = v;
  sB[i] = f2bf(v);
}

// ---------------- transpose W_res -> bf16 [n][k] ----------------
__global__ void k_wres_t(const float* __restrict__ W, short* __restrict__ bt) {
  __shared__ float tile[64][65];
  int k0 = blockIdx.y * 64, n0 = blockIdx.x * 64;
  int tx = threadIdx.x & 63, ty = threadIdx.x >> 6;   // 256 thr
  #pragma unroll
  for (int r = 0; r < 64; r += 4)
    tile[r + ty][tx] = W[(long)(k0 + r + ty) * N_RES + n0 + tx];
  __syncthreads();
  #pragma unroll
  for (int r = 0; r < 64; r += 4)
    bt[(long)(n0 + r + ty) * N_RES + k0 + tx] = f2bf(tile[tx][r + ty]);
}

// ---------------- build B2 = [Whi | Wlo | Whi] rows of [W_in;W_gate] ----------------
__global__ void k_build_b2(const float* __restrict__ Win,
                           const float* __restrict__ Wg, short* __restrict__ B2) {
  int r = blockIdx.x;   // 16384 rows
  const float* src = (r < N_RES) ? (Win + (long)r * IN_DIM)
                                 : (Wg + (long)(r - N_RES) * IN_DIM);
  short* dst = B2 + (long)r * KPRE;
  for (int c = threadIdx.x; c < IN_DIM; c += 256) {
    float x = src[c];
    short h = f2bf(x);
    short l = f2bf(x - bf2f(h));
    dst[c] = h; dst[IN_DIM + c] = l; dst[2 * IN_DIM + c] = h;
  }
}

// ---------------- build A2 chunk = [Xhi | Xhi | Xlo] ----------------
__global__ void k_build_a2(const float* __restrict__ x, short* __restrict__ A2, int t0) {
  int r = blockIdx.x;   // Tc*128 rows
  const float* src = x + (long)(t0 * B_SZ + r) * IN_DIM;
  short* dst = A2 + (long)r * KPRE;
  for (int c = threadIdx.x; c < IN_DIM; c += 256) {
    float v = src[c];
    short h = f2bf(v);
    short l = f2bf(v - bf2f(h));
    dst[c] = h; dst[IN_DIM + c] = h; dst[2 * IN_DIM + c] = l;
  }
}

// ---------------- precompute GEMM: C = A2 @ B2^T  (256x256 8-phase) ----------------
// BM=BN=256, BK=64, 512 thr (8 waves 2Mx4N), per-wave 128x64 out.
// LDS: 2buf x 2half x 128x64 for A and B = 128 KiB. XOR-swizzled (both sides).
// Phases P0..P3 = quadrant (qm,qn); rows qm*128+wr*64, cols qn*128+wc*32 so each
// phase needs exactly one newly-staged half-tile. Stage order (A0,B0,B1,A1) into
// buf^1; per-phase s_waitcnt vmcnt(4)+s_barrier (counted, never 0 in loop).
__global__ __launch_bounds__(512, 2) void k_gemm_pre(
    const short* __restrict__ A2, const short* __restrict__ B2,
    _Float16* __restrict__ ip, _Float16* __restrict__ gates, int Mrows) {
  __shared__ short lA[2][2][128 * 64];
  __shared__ short lB[2][2][128 * 64];
  int tid = threadIdx.x, lane = tid & 63, wid = tid >> 6;
  int wr = wid >> 2, wc = wid & 3;

  // bijective XCD swizzle (m204), mt-major chunks per XCD
  int nwg = gridDim.x, orig = blockIdx.x;
  int qx = nwg >> 3, rx = nwg & 7, xcd = orig & 7;
  int wgid = (xcd < rx ? xcd * (qx + 1) : rx * (qx + 1) + (xcd - rx) * qx) + (orig >> 3);
  int mt = wgid >> 6, nt = wgid & 63;
  long m0 = (long)mt * 256, n0 = (long)nt * 256;
  long mclamp = Mrows - 1;

  // staging: chunk = q8*512+tid; row = chunk>>3 (0..127), colchunk=(chunk&7)^(row&7)
  int c0 = tid, c1 = 512 + tid;
  int r0 = c0 >> 3, r1 = c1 >> 3;
  int cc0 = ((c0 & 7) ^ (r0 & 7)) * 8, cc1 = ((c1 & 7) ^ (r1 & 7)) * 8;

  const short *pA00, *pA01, *pA10, *pA11, *pB00, *pB01, *pB10, *pB11;
  {
    long a00 = m0 + r0;       if (a00 > mclamp) a00 = mclamp;
    long a01 = m0 + r1;       if (a01 > mclamp) a01 = mclamp;
    long a10 = m0 + 128 + r0; if (a10 > mclamp) a10 = mclamp;
    long a11 = m0 + 128 + r1; if (a11 > mclamp) a11 = mclamp;
    pA00 = A2 + a00 * KPRE + cc0;  pA01 = A2 + a01 * KPRE + cc1;
    pA10 = A2 + a10 * KPRE + cc0;  pA11 = A2 + a11 * KPRE + cc1;
    pB00 = B2 + (n0 + r0) * KPRE + cc0;        pB01 = B2 + (n0 + r1) * KPRE + cc1;
    pB10 = B2 + (n0 + 128 + r0) * KPRE + cc0;  pB11 = B2 + (n0 + 128 + r1) * KPRE + cc1;
  }

  #define STG_A0(kt, b) { gload16(pA00 + (kt)*64, &lA[b][0][c0*8]); gload16(pA01 + (kt)*64, &lA[b][0][c1*8]); }
  #define STG_A1(kt, b) { gload16(pA10 + (kt)*64, &lA[b][1][c0*8]); gload16(pA11 + (kt)*64, &lA[b][1][c1*8]); }
  #define STG_B0(kt, b) { gload16(pB00 + (kt)*64, &lB[b][0][c0*8]); gload16(pB01 + (kt)*64, &lB[b][0][c1*8]); }
  #define STG_B1(kt, b) { gload16(pB10 + (kt)*64, &lB[b][1][c0*8]); gload16(pB11 + (kt)*64, &lB[b][1][c1*8]); }

  int lm = lane & 15;
  int colS0 = ((lane >> 4) * 8) ^ ((lane & 7) << 3);
  int colS1 = (32 + (lane >> 4) * 8) ^ ((lane & 7) << 3);
  int arow[4], brow[2];
  #pragma unroll
  for (int i = 0; i < 4; ++i) arow[i] = (wr * 64 + i * 16 + lm) * 64;
  #pragma unroll
  for (int j = 0; j < 2; ++j) brow[j] = (wc * 32 + j * 16 + lm) * 64;

  bf16x8 aF[4][2], bF[2][2];
  f32x4 acc[2][4][4] = {};

  #define RD_A(qm, b) { _Pragma("unroll") for (int i = 0; i < 4; ++i) {        \
      aF[i][0] = *(const bf16x8*)&lA[b][qm][arow[i] + colS0];                  \
      aF[i][1] = *(const bf16x8*)&lA[b][qm][arow[i] + colS1]; } }
  #define RD_B(qn, b) { _Pragma("unroll") for (int j = 0; j < 2; ++j) {        \
      bF[j][0] = *(const bf16x8*)&lB[b][qn][brow[j] + colS0];                  \
      bF[j][1] = *(const bf16x8*)&lB[b][qn][brow[j] + colS1]; } }
  #define MM(qm, qn) { __builtin_amdgcn_s_setprio(1);                          \
      _Pragma("unroll") for (int i = 0; i < 4; ++i)                            \
      _Pragma("unroll") for (int j = 0; j < 2; ++j) {                          \
        acc[qm][i][(qn)*2+j] = __builtin_amdgcn_mfma_f32_16x16x32_bf16(        \
            aF[i][0], bF[j][0], acc[qm][i][(qn)*2+j], 0, 0, 0);                \
        acc[qm][i][(qn)*2+j] = __builtin_amdgcn_mfma_f32_16x16x32_bf16(        \
            aF[i][1], bF[j][1], acc[qm][i][(qn)*2+j], 0, 0, 0); }              \
      __builtin_amdgcn_s_setprio(0); }

  // prologue: stage K-tile 0, order A0,B0,B1,A1 (8 loads in flight)
  STG_A0(0, 0); STG_B0(0, 0); STG_B1(0, 0); STG_A1(0, 0);

  const int nk = KPRE / 64;   // 48
  for (int kt = 0; kt < nk; ++kt) {
    int buf = kt & 1, nbuf = buf ^ 1;
    int ktn = (kt + 1 < nk) ? kt + 1 : kt;   // tail: harmless re-stage, counts uniform
    // P0: quadrant (0,0) — needs A0,B0 of kt (oldest 4 loads)
    asm volatile("s_waitcnt vmcnt(4)\n\ts_barrier" ::: "memory");
    RD_A(0, buf); RD_B(0, buf);
    STG_A0(ktn, nbuf);
    MM(0, 0);
    asm volatile("s_barrier" ::: "memory");
    // P1: (0,1) — needs B1 of kt
    asm volatile("s_waitcnt vmcnt(4)\n\ts_barrier" ::: "memory");
    RD_B(1, buf);
    STG_B0(ktn, nbuf);
    MM(0, 1);
    asm volatile("s_barrier" ::: "memory");
    // P2: (1,0) — needs A1 of kt
    asm volatile("s_waitcnt vmcnt(4)\n\ts_barrier" ::: "memory");
    RD_A(1, buf); RD_B(0, buf);
    STG_B1(ktn, nbuf);
    MM(1, 0);
    asm volatile("s_barrier" ::: "memory");
    // P3: (1,1) — nothing new to wait for
    RD_B(1, buf);
    STG_A1(ktn, nbuf);
    MM(1, 1);
    asm volatile("s_barrier" ::: "memory");
  }
  #undef STG_A0
  #undef STG_A1
  #undef STG_B0
  #undef STG_B1
  #undef RD_A
  #undef RD_B
  #undef MM

  #pragma unroll
  for (int qm = 0; qm < 2; ++qm)
    #pragma unroll
    for (int i = 0; i < 4; ++i)
      #pragma unroll
      for (int qn = 0; qn < 2; ++qn)
        #pragma unroll
        for (int j = 0; j < 2; ++j)
          #pragma unroll
          for (int q = 0; q < 4; ++q) {
            long m = m0 + qm * 128 + wr * 64 + i * 16 + (lane >> 4) * 4 + q;
            long n = n0 + qn * 128 + wc * 32 + j * 16 + lm;
            if (m >= Mrows) continue;
            float v = acc[qm][i][qn * 2 + j][q];
            if (n < N_RES) {
              ip[m * N_RES + n] = (_Float16)v;
            } else {
              gates[m * 12288 + (n - N_RES)] = (_Float16)(1.f / (1.f + __expf(-v)));
            }
          }
}

// ---------------- per-step GEMM: res = prev_bf16 @ WresBT^T + fused epilogue ----
// BM=64 x BN=32, 256 blocks, 512 threads (8 waves = 2/SIMD for latency hiding).
// BK=128, double-buffered LDS (48 KiB), proven 2-phase: stage(t+1) || compute(t).
__global__ __launch_bounds__(512) void k_step(
    const short* __restrict__ Abf,      // state bf16 (read buf)  [128][4096]
    const short* __restrict__ Bt,       // Wres^T bf16 [4096][4096]
    const _Float16* __restrict__ ip,    // + tloc*128*4096
    const _Float16* __restrict__ gates, // + tloc*128*12288
    float* __restrict__ sF,             // state fp32 [128][4096]
    short* __restrict__ sBw,            // state bf16 (write buf)
    float* __restrict__ out) {          // d_out + t*128*4608
  __shared__ short lA[2][64 * 128];     // 2 x 16 KiB
  __shared__ short lB[2][32 * 128];     // 2 x 8 KiB
  int tid = threadIdx.x, lane = tid & 63, wid = tid >> 6;   // 8 waves
  int wm = wid >> 1, wn = wid & 1;      // wave tile: 16 rows (wm*16) x 16 cols (wn*16)

  // XCD-aware mapping: blockIdx%8 = XCD; n-slice pinned per XCD.
  int b = blockIdx.x;                   // 0..255
  int slot = b >> 3;                    // 0..31
  int n_tile = (b & 7) * 16 + (slot & 15);
  int m_half = slot >> 4;
  int n0 = n_tile * 32;
  int m0 = m_half * 64;

  // staging geometry: A tile 64x128 shorts = 1024 16B-chunks (2/thread),
  // B tile 32x128 = 512 chunks (1/thread).
  // chunk c: row=c>>4, src colchunk=(c&15)^(row&7); dest linear c*16B.
  const int cA0 = tid, cA1 = 512 + tid, cB0 = tid;
  const short* pA0 = Abf + (size_t)(m0 + (cA0 >> 4)) * N_RES + (((cA0 & 15) ^ ((cA0 >> 4) & 7)) * 8);
  const short* pA1 = Abf + (size_t)(m0 + (cA1 >> 4)) * N_RES + (((cA1 & 15) ^ ((cA1 >> 4) & 7)) * 8);
  const short* pB0 = Bt  + (size_t)(n0 + (cB0 >> 4)) * N_RES + (((cB0 & 15) ^ ((cB0 >> 4) & 7)) * 8);

  #define STAGE(kt, bi)                                \
    {                                                  \
      int k0s = (kt) * 128;                            \
      gload16(pA0 + k0s, &lA[bi][cA0 * 8]);            \
      gload16(pA1 + k0s, &lA[bi][cA1 * 8]);            \
      gload16(pB0 + k0s, &lB[bi][cB0 * 8]);            \
    }

  f32x4 acc = {};

  STAGE(0, 0);
  asm volatile("s_waitcnt vmcnt(0)" ::: "memory");
  __syncthreads();

  for (int kt = 0; kt < 32; ++kt) {
    int cur = kt & 1;
    if (kt < 31) STAGE(kt + 1, cur ^ 1);
    #pragma unroll
    for (int kk = 0; kk < 128; kk += 32) {
      int colS = (kk + (lane >> 4) * 8) ^ ((lane & 7) << 3);
      bf16x8 aF = *(const bf16x8*)&lA[cur][(wm * 16 + (lane & 15)) * 128 + colS];
      bf16x8 bF = *(const bf16x8*)&lB[cur][(wn * 16 + (lane & 15)) * 128 + colS];
      acc = __builtin_amdgcn_mfma_f32_16x16x32_bf16(aF, bF, acc, 0, 0, 0);
    }
    asm volatile("s_waitcnt vmcnt(0)" ::: "memory");
    __syncthreads();
  }
  #undef STAGE

  #pragma unroll
  for (int q = 0; q < 4; ++q) {
    int m = m0 + wm * 16 + (lane >> 4) * 4 + q;
    int n = n0 + wn * 16 + (lane & 15);
    float res = acc[q];
    long idx = (long)m * N_RES + n;
    float prev = sF[idx];
    float ipv = (float)ip[idx];
    const _Float16* grow = gates + (long)m * 12288 + n;
    float ig = (float)grow[0];
    float fg = (float)grow[4096];
    float og = (float)grow[8192];
    float s = 0.9f * (fg * prev) + 0.1f * tanhf(ig * (ipv + res));
    s = og * s;
    if (s > 0.5f) s -= 0.5f;
    out[(long)m * MAXD + n] = s;
    sF[idx] = s;
    sBw[idx] = f2bf(s);
  }
}

extern "C" void kernel_launch(void* const* d_in, const int* in_sizes, int n_in,
                              void* d_out, int out_size, void* d_ws, size_t ws_size,
                              hipStream_t stream) {
  const float* x      = (const float*)d_in[0];
  const float* state0 = (const float*)d_in[1];
  const float* W_res  = (const float*)d_in[2];
  const float* W_in   = (const float*)d_in[3];
  const float* W_gate = (const float*)d_in[4];
  float* out = (float*)d_out;
  char* ws = (char*)d_ws;

  size_t off = 0;
  short* WresBT = (short*)(ws + off); off += (size_t)N_RES * N_RES * 2;       // 33.6 MB
  short* B2     = (short*)(ws + off); off += (size_t)16384 * KPRE * 2;        // 100.7 MB
  float* sF     = (float*)(ws + off); off += (size_t)B_SZ * N_RES * 4;        // 2 MB
  short* sB0    = (short*)(ws + off); off += (size_t)B_SZ * N_RES * 2;        // 1 MB
  short* sB1    = (short*)(ws + off); off += (size_t)B_SZ * N_RES * 2;        // 1 MB
  size_t fixed = off;
  size_t per = (size_t)B_SZ * KPRE * 2 + (size_t)B_SZ * N_RES * 2 + (size_t)B_SZ * 12288 * 2;

  int Tc = T_STEPS;
  while (Tc > 1 && fixed + (size_t)Tc * per > ws_size) Tc >>= 1;

  short*     A2  = (short*)(ws + fixed);
  _Float16*  ipb = (_Float16*)(ws + fixed + (size_t)Tc * B_SZ * KPRE * 2);
  _Float16*  gtb = (_Float16*)(ws + fixed + (size_t)Tc * B_SZ * KPRE * 2
                               + (size_t)Tc * B_SZ * N_RES * 2);

  k_zero_pad<<<T_STEPS * B_SZ, 128, 0, stream>>>(out);
  k_init_state<<<(B_SZ * N_RES) / 256, 256, 0, stream>>>(state0, sF, sB0);
  k_wres_t<<<dim3(64, 64), 256, 0, stream>>>(W_res, WresBT);
  k_build_b2<<<16384, 256, 0, stream>>>(W_in, W_gate, B2);

  for (int t0 = 0; t0 < T_STEPS; t0 += Tc) {
    k_build_a2<<<Tc * B_SZ, 256, 0, stream>>>(x, A2, t0);
    int Mrows = Tc * B_SZ;
    int mtiles = (Mrows + 255) / 256;
    k_gemm_pre<<<mtiles * 64, 512, 0, stream>>>(A2, B2, ipb, gtb, Mrows);
    for (int tl = 0; tl < Tc; ++tl) {
      int t = t0 + tl;
      const short* Ar = (t & 1) ? sB1 : sB0;
      short*       Aw = (t & 1) ? sB0 : sB1;
      k_step<<<256, 512, 0, stream>>>(
          Ar, WresBT,
          ipb + (size_t)tl * B_SZ * N_RES,
          gtb + (size_t)tl * B_SZ * 12288,
          sF, Aw,
          out + (size_t)t * B_SZ * MAXD);
    }
  }
}

// Round 6
// 5137.497 us; speedup vs baseline: 1.3683x; 1.0807x over previous
//
#include <hip/hip_runtime.h>
#include <hip/hip_bf16.h>
#include <hip/hip_fp16.h>

#define N_RES   4096
#define MAXD    4608
#define IN_DIM  1024
#define T_STEPS 128
#define B_SZ    128
#define KPRE    3072   // 3 * 1024 (hi*hi | hi*lo | lo*hi)

typedef __attribute__((ext_vector_type(8))) short bf16x8;
typedef __attribute__((ext_vector_type(4))) float f32x4;

__device__ __forceinline__ short f2bf(float x) {
  union { float f; unsigned u; } v; v.f = x;
  unsigned r = v.u + 0x7fffu + ((v.u >> 16) & 1u);
  return (short)(r >> 16);
}
__device__ __forceinline__ float bf2f(short b) {
  union { float f; unsigned u; } v; v.u = ((unsigned)(unsigned short)b) << 16;
  return v.f;
}

__device__ __forceinline__ void gload16(const void* g, void* l) {
  __builtin_amdgcn_global_load_lds(
      (const __attribute__((address_space(1))) void*)g,
      (__attribute__((address_space(3))) void*)l,
      16, 0, 0);
}

// ---------------- zero ONLY the padding columns [4096,4608) ----------------
__global__ void k_zero_pad(float* __restrict__ out) {
  int row = blockIdx.x;            // 16384 rows (T*B)
  int t = threadIdx.x;             // 128 threads * float4 = 512 cols
  *(float4*)(out + (size_t)row * MAXD + N_RES + t * 4) = float4{0.f, 0.f, 0.f, 0.f};
}

// ---------------- init state from state0 ----------------
__global__ void k_init_state(const float* __restrict__ s0,
                             float* __restrict__ sF, short* __restrict__ sB) {
  int i = blockIdx.x * 256 + threadIdx.x;   // 128*4096 total
  int m = i >> 12, n = i & 4095;
  float v = s0[m * MAXD + n];
  sF[i] = v;
  sB[i] = f2bf(v);
}

// ---------------- transpose W_res -> bf16 [n][k] ----------------
__global__ void k_wres_t(const float* __restrict__ W, short* __restrict__ bt) {
  __shared__ float tile[64][65];
  int k0 = blockIdx.y * 64, n0 = blockIdx.x * 64;
  int tx = threadIdx.x & 63, ty = threadIdx.x >> 6;   // 256 thr
  #pragma unroll
  for (int r = 0; r < 64; r += 4)
    tile[r + ty][tx] = W[(long)(k0 + r + ty) * N_RES + n0 + tx];
  __syncthreads();
  #pragma unroll
  for (int r = 0; r < 64; r += 4)
    bt[(long)(n0 + r + ty) * N_RES + k0 + tx] = f2bf(tile[tx][r + ty]);
}

// ---------------- build B2 = [Whi | Wlo | Whi] rows of [W_in;W_gate] ----------------
__global__ void k_build_b2(const float* __restrict__ Win,
                           const float* __restrict__ Wg, short* __restrict__ B2) {
  int r = blockIdx.x;   // 16384 rows
  const float* src = (r < N_RES) ? (Win + (long)r * IN_DIM)
                                 : (Wg + (long)(r - N_RES) * IN_DIM);
  short* dst = B2 + (long)r * KPRE;
  for (int c = threadIdx.x; c < IN_DIM; c += 256) {
    float x = src[c];
    short h = f2bf(x);
    short l = f2bf(x - bf2f(h));
    dst[c] = h; dst[IN_DIM + c] = l; dst[2 * IN_DIM + c] = h;
  }
}

// ---------------- build A2 chunk = [Xhi | Xhi | Xlo] ----------------
__global__ void k_build_a2(const float* __restrict__ x, short* __restrict__ A2, int t0) {
  int r = blockIdx.x;   // Tc*128 rows
  const float* src = x + (long)(t0 * B_SZ + r) * IN_DIM;
  short* dst = A2 + (long)r * KPRE;
  for (int c = threadIdx.x; c < IN_DIM; c += 256) {
    float v = src[c];
    short h = f2bf(v);
    short l = f2bf(v - bf2f(h));
    dst[c] = h; dst[IN_DIM + c] = h; dst[2 * IN_DIM + c] = l;
  }
}

// ---------------- precompute GEMM: C = A2 @ B2^T  (256x256 8-phase) ----------------
// BM=BN=256, BK=64, 512 thr (8 waves 2Mx4N), per-wave 128x64 out.
// LDS: 2buf x 2half x 128x64 for A and B = 128 KiB. XOR-swizzled (both sides).
// Phases P0..P3 = quadrant (qm,qn); per-phase s_waitcnt vmcnt(4)+s_barrier.
__global__ __launch_bounds__(512, 2) void k_gemm_pre(
    const short* __restrict__ A2, const short* __restrict__ B2,
    _Float16* __restrict__ ip, _Float16* __restrict__ gates, int Mrows) {
  __shared__ short lA[2][2][128 * 64];
  __shared__ short lB[2][2][128 * 64];
  int tid = threadIdx.x, lane = tid & 63, wid = tid >> 6;
  int wr = wid >> 2, wc = wid & 3;

  // bijective XCD swizzle (m204), mt-major chunks per XCD
  int nwg = gridDim.x, orig = blockIdx.x;
  int qx = nwg >> 3, rx = nwg & 7, xcd = orig & 7;
  int wgid = (xcd < rx ? xcd * (qx + 1) : rx * (qx + 1) + (xcd - rx) * qx) + (orig >> 3);
  int mt = wgid >> 6, nt = wgid & 63;
  long m0 = (long)mt * 256, n0 = (long)nt * 256;
  long mclamp = Mrows - 1;

  // staging: chunk = q8*512+tid; row = chunk>>3 (0..127), colchunk=(chunk&7)^(row&7)
  int c0 = tid, c1 = 512 + tid;
  int r0 = c0 >> 3, r1 = c1 >> 3;
  int cc0 = ((c0 & 7) ^ (r0 & 7)) * 8, cc1 = ((c1 & 7) ^ (r1 & 7)) * 8;

  const short *pA00, *pA01, *pA10, *pA11, *pB00, *pB01, *pB10, *pB11;
  {
    long a00 = m0 + r0;       if (a00 > mclamp) a00 = mclamp;
    long a01 = m0 + r1;       if (a01 > mclamp) a01 = mclamp;
    long a10 = m0 + 128 + r0; if (a10 > mclamp) a10 = mclamp;
    long a11 = m0 + 128 + r1; if (a11 > mclamp) a11 = mclamp;
    pA00 = A2 + a00 * KPRE + cc0;  pA01 = A2 + a01 * KPRE + cc1;
    pA10 = A2 + a10 * KPRE + cc0;  pA11 = A2 + a11 * KPRE + cc1;
    pB00 = B2 + (n0 + r0) * KPRE + cc0;        pB01 = B2 + (n0 + r1) * KPRE + cc1;
    pB10 = B2 + (n0 + 128 + r0) * KPRE + cc0;  pB11 = B2 + (n0 + 128 + r1) * KPRE + cc1;
  }

  #define STG_A0(kt, b) { gload16(pA00 + (kt)*64, &lA[b][0][c0*8]); gload16(pA01 + (kt)*64, &lA[b][0][c1*8]); }
  #define STG_A1(kt, b) { gload16(pA10 + (kt)*64, &lA[b][1][c0*8]); gload16(pA11 + (kt)*64, &lA[b][1][c1*8]); }
  #define STG_B0(kt, b) { gload16(pB00 + (kt)*64, &lB[b][0][c0*8]); gload16(pB01 + (kt)*64, &lB[b][0][c1*8]); }
  #define STG_B1(kt, b) { gload16(pB10 + (kt)*64, &lB[b][1][c0*8]); gload16(pB11 + (kt)*64, &lB[b][1][c1*8]); }

  int lm = lane & 15;
  int colS0 = ((lane >> 4) * 8) ^ ((lane & 7) << 3);
  int colS1 = (32 + (lane >> 4) * 8) ^ ((lane & 7) << 3);
  int arow[4], brow[2];
  #pragma unroll
  for (int i = 0; i < 4; ++i) arow[i] = (wr * 64 + i * 16 + lm) * 64;
  #pragma unroll
  for (int j = 0; j < 2; ++j) brow[j] = (wc * 32 + j * 16 + lm) * 64;

  bf16x8 aF[4][2], bF[2][2];
  f32x4 acc[2][4][4] = {};

  #define RD_A(qm, b) { _Pragma("unroll") for (int i = 0; i < 4; ++i) {        \
      aF[i][0] = *(const bf16x8*)&lA[b][qm][arow[i] + colS0];                  \
      aF[i][1] = *(const bf16x8*)&lA[b][qm][arow[i] + colS1]; } }
  #define RD_B(qn, b) { _Pragma("unroll") for (int j = 0; j < 2; ++j) {        \
      bF[j][0] = *(const bf16x8*)&lB[b][qn][brow[j] + colS0];                  \
      bF[j][1] = *(const bf16x8*)&lB[b][qn][brow[j] + colS1]; } }
  #define MM(qm, qn) { __builtin_amdgcn_s_setprio(1);                          \
      _Pragma("unroll") for (int i = 0; i < 4; ++i)                            \
      _Pragma("unroll") for (int j = 0; j < 2; ++j) {                          \
        acc[qm][i][(qn)*2+j] = __builtin_amdgcn_mfma_f32_16x16x32_bf16(        \
            aF[i][0], bF[j][0], acc[qm][i][(qn)*2+j], 0, 0, 0);                \
        acc[qm][i][(qn)*2+j] = __builtin_amdgcn_mfma_f32_16x16x32_bf16(        \
            aF[i][1], bF[j][1], acc[qm][i][(qn)*2+j], 0, 0, 0); }              \
      __builtin_amdgcn_s_setprio(0); }

  // prologue: stage K-tile 0, order A0,B0,B1,A1 (8 loads in flight)
  STG_A0(0, 0); STG_B0(0, 0); STG_B1(0, 0); STG_A1(0, 0);

  const int nk = KPRE / 64;   // 48
  for (int kt = 0; kt < nk; ++kt) {
    int buf = kt & 1, nbuf = buf ^ 1;
    int ktn = (kt + 1 < nk) ? kt + 1 : kt;   // tail: harmless re-stage, counts uniform
    // P0: quadrant (0,0) — needs A0,B0 of kt (oldest 4 loads)
    asm volatile("s_waitcnt vmcnt(4)\n\ts_barrier" ::: "memory");
    RD_A(0, buf); RD_B(0, buf);
    STG_A0(ktn, nbuf);
    MM(0, 0);
    asm volatile("s_barrier" ::: "memory");
    // P1: (0,1) — needs B1 of kt
    asm volatile("s_waitcnt vmcnt(4)\n\ts_barrier" ::: "memory");
    RD_B(1, buf);
    STG_B0(ktn, nbuf);
    MM(0, 1);
    asm volatile("s_barrier" ::: "memory");
    // P2: (1,0) — needs A1 of kt
    asm volatile("s_waitcnt vmcnt(4)\n\ts_barrier" ::: "memory");
    RD_A(1, buf); RD_B(0, buf);
    STG_B1(ktn, nbuf);
    MM(1, 0);
    asm volatile("s_barrier" ::: "memory");
    // P3: (1,1) — nothing new to wait for
    RD_B(1, buf);
    STG_A1(ktn, nbuf);
    MM(1, 1);
    asm volatile("s_barrier" ::: "memory");
  }
  #undef STG_A0
  #undef STG_A1
  #undef STG_B0
  #undef STG_B1
  #undef RD_A
  #undef RD_B
  #undef MM

  #pragma unroll
  for (int qm = 0; qm < 2; ++qm)
    #pragma unroll
    for (int i = 0; i < 4; ++i)
      #pragma unroll
      for (int qn = 0; qn < 2; ++qn)
        #pragma unroll
        for (int j = 0; j < 2; ++j)
          #pragma unroll
          for (int q = 0; q < 4; ++q) {
            long m = m0 + qm * 128 + wr * 64 + i * 16 + (lane >> 4) * 4 + q;
            long n = n0 + qn * 128 + wc * 32 + j * 16 + lm;
            if (m >= Mrows) continue;
            float v = acc[qm][i][qn * 2 + j][q];
            if (n < N_RES) {
              ip[m * N_RES + n] = (_Float16)v;
            } else {
              gates[m * 12288 + (n - N_RES)] = (_Float16)(1.f / (1.f + __expf(-v)));
            }
          }
}

// ---------------- per-step GEMM: res = prev_bf16 @ WresBT^T + fused epilogue ----
// BM=64 x BN=32, 256 blocks, 512 threads (8 waves = 2/SIMD).
// BK=128, 3-buffer depth-2 counted pipeline: wait vmcnt(3) for loads issued
// 2 compute-phases ago; one s_barrier per K-tile; vmcnt(0) only at the tail.
__global__ __launch_bounds__(512) void k_step(
    const short* __restrict__ Abf,      // state bf16 (read buf)  [128][4096]
    const short* __restrict__ Bt,       // Wres^T bf16 [4096][4096]
    const _Float16* __restrict__ ip,    // + tloc*128*4096
    const _Float16* __restrict__ gates, // + tloc*128*12288
    float* __restrict__ sF,             // state fp32 [128][4096]
    short* __restrict__ sBw,            // state bf16 (write buf)
    float* __restrict__ out) {          // d_out + t*128*4608
  __shared__ short lA[3][64 * 128];     // 3 x 16 KiB
  __shared__ short lB[3][32 * 128];     // 3 x 8 KiB
  int tid = threadIdx.x, lane = tid & 63, wid = tid >> 6;   // 8 waves
  int wm = wid >> 1, wn = wid & 1;      // wave tile: 16 rows (wm*16) x 16 cols (wn*16)

  // XCD-aware mapping: blockIdx%8 = XCD; n-slice pinned per XCD.
  int b = blockIdx.x;                   // 0..255
  int slot = b >> 3;                    // 0..31
  int n_tile = (b & 7) * 16 + (slot & 15);
  int m_half = slot >> 4;
  int n0 = n_tile * 32;
  int m0 = m_half * 64;

  // staging geometry: A tile 64x128 shorts = 1024 16B-chunks (2/thread),
  // B tile 32x128 = 512 chunks (1/thread).
  // chunk c: row=c>>4, src colchunk=(c&15)^(row&7); dest linear c*16B.
  const int cA0 = tid, cA1 = 512 + tid, cB0 = tid;
  const short* pA0 = Abf + (size_t)(m0 + (cA0 >> 4)) * N_RES + (((cA0 & 15) ^ ((cA0 >> 4) & 7)) * 8);
  const short* pA1 = Abf + (size_t)(m0 + (cA1 >> 4)) * N_RES + (((cA1 & 15) ^ ((cA1 >> 4) & 7)) * 8);
  const short* pB0 = Bt  + (size_t)(n0 + (cB0 >> 4)) * N_RES + (((cB0 & 15) ^ ((cB0 >> 4) & 7)) * 8);

  #define STAGE(kt, bi)                                \
    {                                                  \
      int k0s = (kt) * 128;                            \
      gload16(pA0 + k0s, &lA[bi][cA0 * 8]);            \
      gload16(pA1 + k0s, &lA[bi][cA1 * 8]);            \
      gload16(pB0 + k0s, &lB[bi][cB0 * 8]);            \
    }

  #define COMPUTE(bi)                                                          \
    { _Pragma("unroll")                                                        \
      for (int kk = 0; kk < 128; kk += 32) {                                   \
        int colS = (kk + (lane >> 4) * 8) ^ ((lane & 7) << 3);                 \
        bf16x8 aF = *(const bf16x8*)&lA[bi][(wm * 16 + (lane & 15)) * 128 + colS]; \
        bf16x8 bF = *(const bf16x8*)&lB[bi][(wn * 16 + (lane & 15)) * 128 + colS]; \
        acc = __builtin_amdgcn_mfma_f32_16x16x32_bf16(aF, bF, acc, 0, 0, 0);   \
      } }

  f32x4 acc = {};

  STAGE(0, 0);
  STAGE(1, 1);                         // 6 loads in flight

  int bi = 0, sb = 2;
  for (int kt = 0; kt < 31; ++kt) {
    // loads of tile kt are the 3 oldest of 6 in flight -> drain to 3
    asm volatile("s_waitcnt vmcnt(3)" ::: "memory");
    __builtin_amdgcn_s_barrier();      // all waves: tile kt landed, compute(kt-1) done
    if (kt < 30) STAGE(kt + 2, sb);    // overwrites buf computed at kt-1 (safe)
    COMPUTE(bi);
    ++bi; if (bi == 3) bi = 0;
    ++sb; if (sb == 3) sb = 0;
  }
  asm volatile("s_waitcnt vmcnt(0)" ::: "memory");
  __builtin_amdgcn_s_barrier();
  COMPUTE(bi);                         // tile 31 (bi == 1)
  #undef STAGE
  #undef COMPUTE

  #pragma unroll
  for (int q = 0; q < 4; ++q) {
    int m = m0 + wm * 16 + (lane >> 4) * 4 + q;
    int n = n0 + wn * 16 + (lane & 15);
    float res = acc[q];
    long idx = (long)m * N_RES + n;
    float prev = sF[idx];
    float ipv = (float)ip[idx];
    const _Float16* grow = gates + (long)m * 12288 + n;
    float ig = (float)grow[0];
    float fg = (float)grow[4096];
    float og = (float)grow[8192];
    float s = 0.9f * (fg * prev) + 0.1f * tanhf(ig * (ipv + res));
    s = og * s;
    if (s > 0.5f) s -= 0.5f;
    out[(long)m * MAXD + n] = s;
    sF[idx] = s;
    sBw[idx] = f2bf(s);
  }
}

extern "C" void kernel_launch(void* const* d_in, const int* in_sizes, int n_in,
                              void* d_out, int out_size, void* d_ws, size_t ws_size,
                              hipStream_t stream) {
  const float* x      = (const float*)d_in[0];
  const float* state0 = (const float*)d_in[1];
  const float* W_res  = (const float*)d_in[2];
  const float* W_in   = (const float*)d_in[3];
  const float* W_gate = (const float*)d_in[4];
  float* out = (float*)d_out;
  char* ws = (char*)d_ws;

  size_t off = 0;
  short* WresBT = (short*)(ws + off); off += (size_t)N_RES * N_RES * 2;       // 33.6 MB
  short* B2     = (short*)(ws + off); off += (size_t)16384 * KPRE * 2;        // 100.7 MB
  float* sF     = (float*)(ws + off); off += (size_t)B_SZ * N_RES * 4;        // 2 MB
  short* sB0    = (short*)(ws + off); off += (size_t)B_SZ * N_RES * 2;        // 1 MB
  short* sB1    = (short*)(ws + off); off += (size_t)B_SZ * N_RES * 2;        // 1 MB
  size_t fixed = off;
  size_t per = (size_t)B_SZ * KPRE * 2 + (size_t)B_SZ * N_RES * 2 + (size_t)B_SZ * 12288 * 2;

  int Tc = T_STEPS;
  while (Tc > 1 && fixed + (size_t)Tc * per > ws_size) Tc >>= 1;

  short*     A2  = (short*)(ws + fixed);
  _Float16*  ipb = (_Float16*)(ws + fixed + (size_t)Tc * B_SZ * KPRE * 2);
  _Float16*  gtb = (_Float16*)(ws + fixed + (size_t)Tc * B_SZ * KPRE * 2
                               + (size_t)Tc * B_SZ * N_RES * 2);

  k_zero_pad<<<T_STEPS * B_SZ, 128, 0, stream>>>(out);
  k_init_state<<<(B_SZ * N_RES) / 256, 256, 0, stream>>>(state0, sF, sB0);
  k_wres_t<<<dim3(64, 64), 256, 0, stream>>>(W_res, WresBT);
  k_build_b2<<<16384, 256, 0, stream>>>(W_in, W_gate, B2);

  for (int t0 = 0; t0 < T_STEPS; t0 += Tc) {
    k_build_a2<<<Tc * B_SZ, 256, 0, stream>>>(x, A2, t0);
    int Mrows = Tc * B_SZ;
    int mtiles = (Mrows + 255) / 256;
    k_gemm_pre<<<mtiles * 64, 512, 0, stream>>>(A2, B2, ipb, gtb, Mrows);
    for (int tl = 0; tl < Tc; ++tl) {
      int t = t0 + tl;
      const short* Ar = (t & 1) ? sB1 : sB0;
      short*       Aw = (t & 1) ? sB0 : sB1;
      k_step<<<256, 512, 0, stream>>>(
          Ar, WresBT,
          ipb + (size_t)tl * B_SZ * N_RES,
          gtb + (size_t)tl * B_SZ * 12288,
          sF, Aw,
          out + (size_t)t * B_SZ * MAXD);
    }
  }
}